// Round 1
// baseline (552.732 us; speedup 1.0000x reference)
//
#include <hip/hip_runtime.h>

#define N_NODES 200000
#define DIM 256
#define G_SEG 1024
#define MT 128        // rows per block
#define LDA 264       // LDS row stride in bf16 elems (256 + 8 pad)
#define NT 8          // 16-row m-tiles per block
#define KSTEPS 8      // 256 / 32

typedef __bf16 bf16x8 __attribute__((ext_vector_type(8)));
typedef float f32x4 __attribute__((ext_vector_type(4)));
typedef unsigned short us8_t __attribute__((ext_vector_type(8)));
typedef unsigned short us4_t __attribute__((ext_vector_type(4)));

__device__ __forceinline__ unsigned short f2bf(float f) {
  unsigned int u = __float_as_uint(f);
  u = u + 0x7FFFu + ((u >> 16) & 1u);   // round-to-nearest-even
  return (unsigned short)(u >> 16);
}

__device__ __forceinline__ bf16x8 ld_frag(const unsigned short* p) {
  us8_t r = *(const us8_t*)p;
  return __builtin_bit_cast(bf16x8, r);
}

__device__ __forceinline__ float silu(float v) {
  return v / (1.f + __expf(-v));
}

// Stage 128 rows x 256 cols of fp32 X into LDS as bf16 (padded stride LDA).
__device__ __forceinline__ void stage_x(const float* __restrict__ X,
                                        unsigned short* A, int base, int tid) {
  #pragma unroll 4
  for (int i = 0; i < 32; ++i) {
    int flat = i * 256 + tid;          // 0..8191
    int row = flat >> 6;               // 0..127
    int c4 = flat & 63;                // float4 index within row
    int grow = base + row;
    float4 v = make_float4(0.f, 0.f, 0.f, 0.f);
    if (grow < N_NODES) v = *(const float4*)(X + (size_t)grow * DIM + c4 * 4);
    us4_t h;
    h[0] = f2bf(v.x); h[1] = f2bf(v.y); h[2] = f2bf(v.z); h[3] = f2bf(v.w);
    *(us4_t*)(A + row * LDA + c4 * 4) = h;
  }
}

// One K=256 GEMM: this wave computes rows [0,128) x cols [wcol0, wcol0+64)
// A in LDS (row-major, stride LDA), W in global, layout [n][k] (transposed).
__device__ __forceinline__ void gemm_k256(const unsigned short* __restrict__ Wb,
                                          const unsigned short* A,
                                          f32x4 acc[NT][4],
                                          int wcol0, int quad, int l15) {
  for (int ks = 0; ks < KSTEPS; ++ks) {
    int koff = ks * 32 + quad * 8;
    bf16x8 bfr[4];
    #pragma unroll
    for (int u = 0; u < 4; ++u)
      bfr[u] = ld_frag(Wb + (size_t)(wcol0 + u * 16 + l15) * 256 + koff);
    #pragma unroll
    for (int t = 0; t < NT; ++t) {
      bf16x8 afr = ld_frag(A + (t * 16 + l15) * LDA + koff);
      #pragma unroll
      for (int u = 0; u < 4; ++u)
        acc[t][u] = __builtin_amdgcn_mfma_f32_16x16x32_bf16(afr, bfr[u], acc[t][u], 0, 0, 0);
    }
  }
}

__device__ __forceinline__ void zero_acc(f32x4 acc[NT][4]) {
  #pragma unroll
  for (int t = 0; t < NT; ++t)
    #pragma unroll
    for (int u = 0; u < 4; ++u)
      acc[t][u] = (f32x4){0.f, 0.f, 0.f, 0.f};
}

// Kernel 0: zero out + denom, convert weights to bf16 transposed [n][k].
__global__ void k_prep(const float* __restrict__ W1, const float* __restrict__ W2,
                       const float* __restrict__ W3, const float* __restrict__ aW1,
                       unsigned short* __restrict__ Wb1, unsigned short* __restrict__ Wb2,
                       unsigned short* __restrict__ Wb3, unsigned short* __restrict__ aWb1,
                       float* __restrict__ out, float* __restrict__ denom) {
  int idx = blockIdx.x * blockDim.x + threadIdx.x;   // grid covers 262144
  out[idx] = 0.f;
  if (idx < G_SEG) denom[idx] = 0.f;
  if (idx < 65536) {
    int k = idx >> 8, n = idx & 255;
    int d = n * 256 + k;
    Wb1[d] = f2bf(W1[idx]);
    Wb2[d] = f2bf(W2[idx]);
    Wb3[d] = f2bf(W3[idx]);
    aWb1[d] = f2bf(aW1[idx]);
  }
}

// Kernel 1: attention logits -> ew = exp(logit), per-segment denom sums.
__global__ __launch_bounds__(256, 2) void k_attn(
    const float* __restrict__ X, const int* __restrict__ batch,
    const unsigned short* __restrict__ aWb1, const float* __restrict__ ab1,
    const float* __restrict__ aW2, const float* __restrict__ ab2,
    float* __restrict__ ew, float* __restrict__ denom) {
  __shared__ unsigned short a_lds[MT * LDA];
  __shared__ float l_lds[MT];
  __shared__ float seg_lds[4];
  int tid = threadIdx.x;
  int base = blockIdx.x * MT;
  stage_x(X, a_lds, base, tid);
  if (tid < MT) l_lds[tid] = 0.f;
  if (tid < 4) seg_lds[tid] = 0.f;
  __syncthreads();

  int wave = tid >> 6, lane = tid & 63, quad = lane >> 4, l15 = lane & 15;
  int wcol0 = wave * 64;
  f32x4 acc[NT][4];
  zero_acc(acc);
  gemm_k256(aWb1, a_lds, acc, wcol0, quad, l15);

  float ab1c[4], aw2c[4];
  #pragma unroll
  for (int u = 0; u < 4; ++u) {
    int c = wcol0 + u * 16 + l15;
    ab1c[u] = ab1[c];
    aw2c[u] = aW2[c];
  }
  #pragma unroll
  for (int t = 0; t < NT; ++t) {
    #pragma unroll
    for (int r = 0; r < 4; ++r) {
      float p = 0.f;
      #pragma unroll
      for (int u = 0; u < 4; ++u) {
        float v = acc[t][u][r] + ab1c[u];
        p += silu(v) * aw2c[u];
      }
      // sum the 16 cols held by this quad
      p += __shfl_xor(p, 1); p += __shfl_xor(p, 2);
      p += __shfl_xor(p, 4); p += __shfl_xor(p, 8);
      if (l15 == 0) atomicAdd(&l_lds[t * 16 + quad * 4 + r], p);
    }
  }
  __syncthreads();
  if (tid < MT) {
    int grow = base + tid;
    if (grow < N_NODES) {
      float e = __expf(l_lds[tid] + ab2[0]);
      ew[grow] = e;
      int ds = batch[grow] - batch[base];   // 0 or 1 (seg size >= 195)
      atomicAdd(&seg_lds[ds], e);
    }
  }
  __syncthreads();
  if (tid < 4) {
    float v = seg_lds[tid];
    if (v != 0.f) atomicAdd(&denom[batch[base] + tid], v);
  }
}

// Kernel 2: 3-GEMM MLP chain + weighted segment-sum readout.
__global__ __launch_bounds__(256, 2) void k_mlp(
    const float* __restrict__ X, const int* __restrict__ batch,
    const unsigned short* __restrict__ Wb1, const float* __restrict__ b1,
    const unsigned short* __restrict__ Wb2, const float* __restrict__ b2,
    const unsigned short* __restrict__ Wb3, const float* __restrict__ b3,
    const float* __restrict__ ew, const float* __restrict__ denom,
    float* __restrict__ out) {
  __shared__ unsigned short a_lds[MT * LDA];
  __shared__ float w0_lds[MT], w1_lds[MT];
  int tid = threadIdx.x;
  int base = blockIdx.x * MT;
  stage_x(X, a_lds, base, tid);
  if (tid < MT) {
    int grow = base + tid;
    float wv = 0.f; int dseg = 0;
    if (grow < N_NODES) {
      int s = batch[grow];
      wv = ew[grow] / denom[s];
      dseg = s - batch[base];
    } else {
      dseg = 1;  // route OOB rows to w1 with wv=0 (harmless either way)
    }
    w0_lds[tid] = (dseg == 0) ? wv : 0.f;
    w1_lds[tid] = (dseg != 0) ? wv : 0.f;
  }
  __syncthreads();

  int wave = tid >> 6, lane = tid & 63, quad = lane >> 4, l15 = lane & 15;
  int wcol0 = wave * 64;
  f32x4 acc[NT][4];

  // ---- stage 1: h1 = silu(X @ W1 + b1) ----
  zero_acc(acc);
  gemm_k256(Wb1, a_lds, acc, wcol0, quad, l15);
  {
    float bc[4];
    #pragma unroll
    for (int u = 0; u < 4; ++u) bc[u] = b1[wcol0 + u * 16 + l15];
    __syncthreads();   // all waves done reading a_lds
    #pragma unroll
    for (int t = 0; t < NT; ++t)
      #pragma unroll
      for (int u = 0; u < 4; ++u)
        #pragma unroll
        for (int r = 0; r < 4; ++r) {
          float v = silu(acc[t][u][r] + bc[u]);
          a_lds[(t * 16 + quad * 4 + r) * LDA + wcol0 + u * 16 + l15] = f2bf(v);
        }
    __syncthreads();
  }

  // ---- stage 2: h2 = silu(h1 @ W2 + b2) ----
  zero_acc(acc);
  gemm_k256(Wb2, a_lds, acc, wcol0, quad, l15);
  {
    float bc[4];
    #pragma unroll
    for (int u = 0; u < 4; ++u) bc[u] = b2[wcol0 + u * 16 + l15];
    __syncthreads();
    #pragma unroll
    for (int t = 0; t < NT; ++t)
      #pragma unroll
      for (int u = 0; u < 4; ++u)
        #pragma unroll
        for (int r = 0; r < 4; ++r) {
          float v = silu(acc[t][u][r] + bc[u]);
          a_lds[(t * 16 + quad * 4 + r) * LDA + wcol0 + u * 16 + l15] = f2bf(v);
        }
    __syncthreads();
  }

  // ---- stage 3: x = h2 @ W3 + b3, then weighted segment reduce ----
  zero_acc(acc);
  gemm_k256(Wb3, a_lds, acc, wcol0, quad, l15);
  float bc[4];
  #pragma unroll
  for (int u = 0; u < 4; ++u) bc[u] = b3[wcol0 + u * 16 + l15];

  int s0 = batch[base];
  float s0a[4] = {0.f, 0.f, 0.f, 0.f};
  float s1a[4] = {0.f, 0.f, 0.f, 0.f};
  #pragma unroll
  for (int t = 0; t < NT; ++t) {
    #pragma unroll
    for (int r = 0; r < 4; ++r) {
      int row = t * 16 + quad * 4 + r;
      float w0 = w0_lds[row], w1 = w1_lds[row];
      #pragma unroll
      for (int u = 0; u < 4; ++u) {
        float v = acc[t][u][r] + bc[u];
        s0a[u] += v * w0;
        s1a[u] += v * w1;
      }
    }
  }
  #pragma unroll
  for (int u = 0; u < 4; ++u) {
    float a0 = s0a[u]; a0 += __shfl_xor(a0, 16); a0 += __shfl_xor(a0, 32);
    float a1 = s1a[u]; a1 += __shfl_xor(a1, 16); a1 += __shfl_xor(a1, 32);
    if (quad == 0) {
      int col = wcol0 + u * 16 + l15;
      atomicAdd(&out[(size_t)s0 * 256 + col], a0);
      if (s0 + 1 < G_SEG && a1 != 0.f)
        atomicAdd(&out[(size_t)(s0 + 1) * 256 + col], a1);
    }
  }
}

extern "C" void kernel_launch(void* const* d_in, const int* in_sizes, int n_in,
                              void* d_out, int out_size, void* d_ws, size_t ws_size,
                              hipStream_t stream) {
  const float* X    = (const float*)d_in[0];
  const int* batch  = (const int*)d_in[1];
  // d_in[2] = num_segments (1024, hardcoded)
  const float* W1  = (const float*)d_in[3];
  const float* b1  = (const float*)d_in[4];
  const float* W2  = (const float*)d_in[5];
  const float* b2  = (const float*)d_in[6];
  const float* W3  = (const float*)d_in[7];
  const float* b3  = (const float*)d_in[8];
  const float* aW1 = (const float*)d_in[9];
  const float* ab1 = (const float*)d_in[10];
  const float* aW2 = (const float*)d_in[11];
  const float* ab2 = (const float*)d_in[12];
  float* out = (float*)d_out;

  char* ws = (char*)d_ws;
  unsigned short* Wb1  = (unsigned short*)(ws);
  unsigned short* Wb2  = (unsigned short*)(ws + 131072);
  unsigned short* Wb3  = (unsigned short*)(ws + 262144);
  unsigned short* aWb1 = (unsigned short*)(ws + 393216);
  float* ew    = (float*)(ws + 524288);
  float* denom = (float*)(ws + 524288 + 800000);

  hipLaunchKernelGGL(k_prep, dim3(1024), dim3(256), 0, stream,
                     W1, W2, W3, aW1, Wb1, Wb2, Wb3, aWb1, out, denom);
  int nblk = (N_NODES + MT - 1) / MT;  // 1563
  hipLaunchKernelGGL(k_attn, dim3(nblk), dim3(256), 0, stream,
                     X, batch, aWb1, ab1, aW2, ab2, ew, denom);
  hipLaunchKernelGGL(k_mlp, dim3(nblk), dim3(256), 0, stream,
                     X, batch, Wb1, b1, Wb2, b2, Wb3, b3, ew, denom, out);
}

// Round 2
// 472.822 us; speedup vs baseline: 1.1690x; 1.1690x over previous
//
#include <hip/hip_runtime.h>

#define N_NODES 200000
#define DIM 256
#define G_SEG 1024
#define MT 128        // rows per block
#define LDA 264       // LDS row stride in bf16 elems (256 + 8 pad)
#define NT 8          // 16-row m-tiles per block
#define KSTEPS 8      // 256 / 32

typedef __bf16 bf16x8 __attribute__((ext_vector_type(8)));
typedef float f32x4 __attribute__((ext_vector_type(4)));
typedef unsigned short us16_t __attribute__((ext_vector_type(16)));
typedef unsigned short us8_t __attribute__((ext_vector_type(8)));
typedef unsigned short us4_t __attribute__((ext_vector_type(4)));

__device__ __forceinline__ unsigned short f2bf(float f) {
  unsigned int u = __float_as_uint(f);
  u = u + 0x7FFFu + ((u >> 16) & 1u);   // round-to-nearest-even
  return (unsigned short)(u >> 16);
}

__device__ __forceinline__ bf16x8 ld_frag(const unsigned short* p) {
  us8_t r = *(const us8_t*)p;
  return __builtin_bit_cast(bf16x8, r);
}

__device__ __forceinline__ float silu(float v) {
  // v * rcp(1+exp(-v)); rcp approx (~1ulp) is far below bf16 noise
  return v * __builtin_amdgcn_rcpf(1.f + __expf(-v));
}

// Stage 128 rows x 256 cols of fp32 X into LDS as bf16 (padded stride LDA).
__device__ __forceinline__ void stage_x(const float* __restrict__ X,
                                        unsigned short* A, int base, int tid) {
  #pragma unroll 4
  for (int i = 0; i < 32; ++i) {
    int flat = i * 256 + tid;          // 0..8191
    int row = flat >> 6;               // 0..127
    int c4 = flat & 63;                // float4 index within row
    int grow = base + row;
    float4 v = make_float4(0.f, 0.f, 0.f, 0.f);
    if (grow < N_NODES) v = *(const float4*)(X + (size_t)grow * DIM + c4 * 4);
    us4_t h;
    h[0] = f2bf(v.x); h[1] = f2bf(v.y); h[2] = f2bf(v.z); h[3] = f2bf(v.w);
    *(us4_t*)(A + row * LDA + c4 * 4) = h;
  }
}

// Transposed GEMM: D[feature][node] = W_tile x X_tile.
// A-operand = W fragment (features m), B-operand = X fragment (nodes n).
// acc[t][u]: node = t*16 + (lane&15), feature = wcol0 + u*16 + (lane>>4)*4 + r.
__device__ __forceinline__ void gemm_k256_T(const unsigned short* __restrict__ Wb,
                                            const unsigned short* A,
                                            f32x4 acc[NT][4],
                                            int wcol0, int quad, int l15) {
  for (int ks = 0; ks < KSTEPS; ++ks) {
    int koff = ks * 32 + quad * 8;
    bf16x8 wfr[4];
    #pragma unroll
    for (int u = 0; u < 4; ++u)
      wfr[u] = ld_frag(Wb + (size_t)(wcol0 + u * 16 + l15) * 256 + koff);
    #pragma unroll
    for (int t = 0; t < NT; ++t) {
      bf16x8 xfr = ld_frag(A + (t * 16 + l15) * LDA + koff);
      #pragma unroll
      for (int u = 0; u < 4; ++u)
        acc[t][u] = __builtin_amdgcn_mfma_f32_16x16x32_bf16(wfr[u], xfr, acc[t][u], 0, 0, 0);
    }
  }
}

__device__ __forceinline__ void zero_acc(f32x4 acc[NT][4]) {
  #pragma unroll
  for (int t = 0; t < NT; ++t)
    #pragma unroll
    for (int u = 0; u < 4; ++u)
      acc[t][u] = (f32x4){0.f, 0.f, 0.f, 0.f};
}

// Kernel 0: zero out + denom (blocks 0..1024), transpose weights to bf16 [n][k]
// with coalesced LDS tiles (blocks 1025..1040).
__global__ __launch_bounds__(256) void k_prep(
    const float* __restrict__ W1, const float* __restrict__ W2,
    const float* __restrict__ W3, const float* __restrict__ aW1,
    unsigned short* __restrict__ Wb1, unsigned short* __restrict__ Wb2,
    unsigned short* __restrict__ Wb3, unsigned short* __restrict__ aWb1,
    float* __restrict__ out, float* __restrict__ denom) {
  __shared__ float tlds[64][257];
  int b = blockIdx.x, tid = threadIdx.x;
  if (b < 1024) {
    out[b * 256 + tid] = 0.f;
    return;
  }
  if (b == 1024) {
    #pragma unroll
    for (int i = 0; i < 4; ++i) denom[tid * 4 + i] = 0.f;
    return;
  }
  int bb = b - 1025;                  // 0..15
  int mat = bb >> 2, kc = bb & 3, k0 = kc * 64;
  const float* W = (mat == 0) ? W1 : (mat == 1) ? W2 : (mat == 2) ? W3 : aW1;
  unsigned short* Wb = (mat == 0) ? Wb1 : (mat == 1) ? Wb2 : (mat == 2) ? Wb3 : aWb1;
  #pragma unroll 8
  for (int i = 0; i < 64; ++i)
    tlds[i][tid] = W[(size_t)(k0 + i) * 256 + tid];
  __syncthreads();
  #pragma unroll
  for (int rep = 0; rep < 4; ++rep) {
    int flat = rep * 256 + tid;       // 0..1023
    int n = flat >> 2, c = flat & 3;
    us16_t v;
    #pragma unroll
    for (int j = 0; j < 16; ++j) v[j] = f2bf(tlds[c * 16 + j][n]);
    *(us16_t*)(Wb + (size_t)n * 256 + k0 + c * 16) = v;
  }
}

// Fused heavy kernel: one staging of X, attention GEMM + 3-stage MLP,
// unnormalized weighted segment sums into out + denom.
__global__ __launch_bounds__(256, 2) void k_fused(
    const float* __restrict__ X, const int* __restrict__ batch,
    const unsigned short* __restrict__ aWb1, const float* __restrict__ ab1,
    const float* __restrict__ aW2, const float* __restrict__ ab2,
    const unsigned short* __restrict__ Wb1, const float* __restrict__ b1,
    const unsigned short* __restrict__ Wb2, const float* __restrict__ b2,
    const unsigned short* __restrict__ Wb3, const float* __restrict__ b3,
    float* __restrict__ out, float* __restrict__ denom) {
  __shared__ unsigned short a_lds[MT * LDA];
  __shared__ float l_lds[MT];
  __shared__ float ew0[MT], ew1[MT];
  __shared__ float seg_lds[2];
  int tid = threadIdx.x;
  int base = blockIdx.x * MT;
  stage_x(X, a_lds, base, tid);
  if (tid < MT) l_lds[tid] = 0.f;
  if (tid < 2) seg_lds[tid] = 0.f;
  __syncthreads();

  int wave = tid >> 6, lane = tid & 63, quad = lane >> 4, l15 = lane & 15;
  int wcol0 = wave * 64;
  int fq = wcol0 + quad * 4;          // this lane's feature base for u=0
  f32x4 acc[NT][4];

  // ---- attention logits GEMM ----
  zero_acc(acc);
  gemm_k256_T(aWb1, a_lds, acc, wcol0, quad, l15);
  {
    float4 ab1c[4], aw2c[4];
    #pragma unroll
    for (int u = 0; u < 4; ++u) {
      ab1c[u] = *(const float4*)(ab1 + fq + u * 16);
      aw2c[u] = *(const float4*)(aW2 + fq + u * 16);
    }
    #pragma unroll
    for (int t = 0; t < NT; ++t) {
      float p = 0.f;
      #pragma unroll
      for (int u = 0; u < 4; ++u) {
        const float* bb = (const float*)&ab1c[u];
        const float* ww = (const float*)&aw2c[u];
        #pragma unroll
        for (int r = 0; r < 4; ++r)
          p += silu(acc[t][u][r] + bb[r]) * ww[r];
      }
      p += __shfl_xor(p, 16); p += __shfl_xor(p, 32);
      if (quad == 0) atomicAdd(&l_lds[t * 16 + l15], p);
    }
  }

  // ---- MLP stage 1: h1 = silu(X @ W1 + b1) ----
  zero_acc(acc);
  gemm_k256_T(Wb1, a_lds, acc, wcol0, quad, l15);
  __syncthreads();   // all waves done with a_lds reads AND l_lds atomics
  if (tid < MT) {
    int grow = base + tid;
    float e = 0.f; int ds = 0;
    if (grow < N_NODES) {
      e = __expf(l_lds[tid] + ab2[0]);
      ds = batch[grow] - batch[base];   // 0 or 1 (min seg size 195 > 128)
    }
    ew0[tid] = ds ? 0.f : e;
    ew1[tid] = ds ? e : 0.f;
    if (e != 0.f) atomicAdd(&seg_lds[ds], e);
  }
  {
    float4 bc[4];
    #pragma unroll
    for (int u = 0; u < 4; ++u) bc[u] = *(const float4*)(b1 + fq + u * 16);
    #pragma unroll
    for (int t = 0; t < NT; ++t)
      #pragma unroll
      for (int u = 0; u < 4; ++u) {
        const float* bb = (const float*)&bc[u];
        us4_t h;
        #pragma unroll
        for (int r = 0; r < 4; ++r)
          h[r] = f2bf(silu(acc[t][u][r] + bb[r]));
        *(us4_t*)(a_lds + (t * 16 + l15) * LDA + fq + u * 16) = h;
      }
  }
  __syncthreads();

  // ---- MLP stage 2: h2 = silu(h1 @ W2 + b2) ----
  zero_acc(acc);
  gemm_k256_T(Wb2, a_lds, acc, wcol0, quad, l15);
  __syncthreads();
  {
    float4 bc[4];
    #pragma unroll
    for (int u = 0; u < 4; ++u) bc[u] = *(const float4*)(b2 + fq + u * 16);
    #pragma unroll
    for (int t = 0; t < NT; ++t)
      #pragma unroll
      for (int u = 0; u < 4; ++u) {
        const float* bb = (const float*)&bc[u];
        us4_t h;
        #pragma unroll
        for (int r = 0; r < 4; ++r)
          h[r] = f2bf(silu(acc[t][u][r] + bb[r]));
        *(us4_t*)(a_lds + (t * 16 + l15) * LDA + fq + u * 16) = h;
      }
  }
  __syncthreads();

  // ---- MLP stage 3: x = h2 @ W3 + b3, weighted segment reduce ----
  zero_acc(acc);
  gemm_k256_T(Wb3, a_lds, acc, wcol0, quad, l15);
  {
    float4 bc[4];
    #pragma unroll
    for (int u = 0; u < 4; ++u) bc[u] = *(const float4*)(b3 + fq + u * 16);
    float s0a[4][4], s1a[4][4];
    #pragma unroll
    for (int u = 0; u < 4; ++u)
      #pragma unroll
      for (int r = 0; r < 4; ++r) { s0a[u][r] = 0.f; s1a[u][r] = 0.f; }
    #pragma unroll
    for (int t = 0; t < NT; ++t) {
      float w0 = ew0[t * 16 + l15];
      float w1 = ew1[t * 16 + l15];
      #pragma unroll
      for (int u = 0; u < 4; ++u) {
        const float* bb = (const float*)&bc[u];
        #pragma unroll
        for (int r = 0; r < 4; ++r) {
          float x = acc[t][u][r] + bb[r];
          s0a[u][r] += x * w0;
          s1a[u][r] += x * w1;
        }
      }
    }
    int s0 = batch[base];
    #pragma unroll
    for (int u = 0; u < 4; ++u)
      #pragma unroll
      for (int r = 0; r < 4; ++r) {
        float a0 = s0a[u][r];
        a0 += __shfl_xor(a0, 1); a0 += __shfl_xor(a0, 2);
        a0 += __shfl_xor(a0, 4); a0 += __shfl_xor(a0, 8);
        float a1 = s1a[u][r];
        a1 += __shfl_xor(a1, 1); a1 += __shfl_xor(a1, 2);
        a1 += __shfl_xor(a1, 4); a1 += __shfl_xor(a1, 8);
        if (l15 == 0) {
          int col = fq + u * 16 + r;
          atomicAdd(&out[(size_t)s0 * 256 + col], a0);
          if (s0 + 1 < G_SEG && a1 != 0.f)
            atomicAdd(&out[(size_t)(s0 + 1) * 256 + col], a1);
        }
      }
    if (tid < 2) {
      float v = seg_lds[tid];
      if (v != 0.f) atomicAdd(&denom[s0 + tid], v);
    }
  }
}

// Kernel 2: out[g][c] /= denom[g]
__global__ __launch_bounds__(256) void k_final(float* __restrict__ out,
                                               const float* __restrict__ denom) {
  int b = blockIdx.x, tid = threadIdx.x;
  float d = denom[b];
  out[b * 256 + tid] *= __builtin_amdgcn_rcpf(d) * (d * __builtin_amdgcn_rcpf(d) > 0.f ? 1.f : 1.f);
}

extern "C" void kernel_launch(void* const* d_in, const int* in_sizes, int n_in,
                              void* d_out, int out_size, void* d_ws, size_t ws_size,
                              hipStream_t stream) {
  const float* X    = (const float*)d_in[0];
  const int* batch  = (const int*)d_in[1];
  const float* W1  = (const float*)d_in[3];
  const float* b1  = (const float*)d_in[4];
  const float* W2  = (const float*)d_in[5];
  const float* b2  = (const float*)d_in[6];
  const float* W3  = (const float*)d_in[7];
  const float* b3  = (const float*)d_in[8];
  const float* aW1 = (const float*)d_in[9];
  const float* ab1 = (const float*)d_in[10];
  const float* aW2 = (const float*)d_in[11];
  const float* ab2 = (const float*)d_in[12];
  float* out = (float*)d_out;

  char* ws = (char*)d_ws;
  unsigned short* Wb1  = (unsigned short*)(ws);
  unsigned short* Wb2  = (unsigned short*)(ws + 131072);
  unsigned short* Wb3  = (unsigned short*)(ws + 262144);
  unsigned short* aWb1 = (unsigned short*)(ws + 393216);
  float* denom = (float*)(ws + 524288);

  hipLaunchKernelGGL(k_prep, dim3(1041), dim3(256), 0, stream,
                     W1, W2, W3, aW1, Wb1, Wb2, Wb3, aWb1, out, denom);
  int nblk = (N_NODES + MT - 1) / MT;  // 1563
  hipLaunchKernelGGL(k_fused, dim3(nblk), dim3(256), 0, stream,
                     X, batch, aWb1, ab1, aW2, ab2,
                     Wb1, b1, Wb2, b2, Wb3, b3, out, denom);
  hipLaunchKernelGGL(k_final, dim3(G_SEG), dim3(256), 0, stream, out, denom);
}